// Round 2
// baseline (507.209 us; speedup 1.0000x reference)
//
#include <hip/hip_runtime.h>

// Problem (all fp32 in/out): x1[o,n,c] = sum_p X[n,p] * (dags*W)[o,p,c]
//          plus dags passthrough and reg[o] = 0.001*sum(W^2).
// N=200000, D=64 (P=C=64), O=8.
// d_out (fp32): x1 (102,400,000) | dags (32,768) | reg (8).
//
// Round-2 findings baked in:
//  - The 1.639 GB workspace poison fill (~261 us) is UNCONDITIONAL (round 1
//    proved it: d_ws unused, fill unchanged). Don't try to dodge it; use d_ws.
//  - NT loads/stores + stash-in-d_out regressed (457 -> 495): reverted.
//  - NEW: no LDS staging in the gemm. WMt is 64 KB and permanently L2-resident
//    (every block re-reads it either way); loading A-fragments straight from
//    L2 removes all 4 barriers + staging per block -> free-flowing
//    load->MFMA->store streams (Common-mistake #7: don't stage L2-fit data).

typedef short short8 __attribute__((ext_vector_type(8)));   // 8 bf16 = 4 VGPRs (MFMA A/B frag)
typedef float f32x4 __attribute__((ext_vector_type(4)));    // MFMA C/D frag / float4

#define NROWS    200000
#define DAGS_OFF 102400000
#define REG_OFF  102432768
#define O_STRIDE 12800000    // 200000*64

__device__ __forceinline__ unsigned short f2bf(float f) {
    union { float f; unsigned int i; } v; v.f = f;
    unsigned int x = v.i;
    unsigned int r = (x + 0x7fffu + ((x >> 16) & 1u)) >> 16;   // RNE
    return (unsigned short)r;
}

// ---------------------------------------------------------------------------
// Prep: WMt[o][c][p] = bf16(dags[o][p][c] * W[o][p][c]) into ws (64 KB),
//       dags fp32 passthrough, reg[o] = 0.001 * sum(W[o]^2) fp32.
// One block per o, 256 threads.
// ---------------------------------------------------------------------------
__global__ __launch_bounds__(256) void prep_kernel(
    const float* __restrict__ dags,
    const float* __restrict__ W,
    unsigned short* __restrict__ wmt,
    float* __restrict__ out)
{
    const int o = blockIdx.x;
    const int t = threadIdx.x;
    const float* dg = dags + o * 4096;
    const float* w  = W    + o * 4096;
    unsigned short* wt = wmt + o * 4096;
    float* outd = out + DAGS_OFF + o * 4096;

    float s = 0.f;
    #pragma unroll
    for (int i = 0; i < 16; ++i) {
        int e = i * 256 + t;          // e = p*64 + c  (coalesced fp32 reads)
        int p = e >> 6, c = e & 63;
        float dv = dg[e];
        float wv = w[e];
        wt[c * 64 + p] = f2bf(dv * wv);   // transposed bf16 write (tiny, L2-resident)
        outd[e] = dv;                      // dags passthrough
        s += wv * wv;
    }
    // block reduction for reg
    #pragma unroll
    for (int off = 32; off > 0; off >>= 1) s += __shfl_down(s, off);
    __shared__ float red[4];
    if ((t & 63) == 0) red[t >> 6] = s;
    __syncthreads();
    if (t == 0) {
        out[REG_OFF + o] = 0.001f * (red[0] + red[1] + red[2] + red[3]);
    }
}

// ---------------------------------------------------------------------------
// Main: per block 64 rows of X, all 8 o's. MFMA 16x16x32 bf16, transposed
// trick: A = WMt tile (c-major, straight from L2), B = X rows. D lane holds
// fixed row n=lane&15, 4 consecutive c per reg-quad -> float4 stores.
// No LDS, no barriers: pure streaming.
// ---------------------------------------------------------------------------
__global__ __launch_bounds__(256, 4) void gemm_kernel(
    const float* __restrict__ X,
    const unsigned short* __restrict__ wmt,
    float* __restrict__ out)
{
    const int t    = threadIdx.x;
    const int w    = t >> 6;        // wave 0..3
    const int lane = t & 63;
    const int r    = lane & 15;     // B col (X row within tile) / A row (c)
    const int q    = lane >> 4;     // quad 0..3

    const int nb = blockIdx.x * 64 + w * 16 + r;   // this lane's X row

    // X fragment (MFMA B operand): lane holds X[nb][k], k = q*8..q*8+7 (+32).
    // fp32 loads (4x16B, full-line coalesced per quad), convert to bf16 in
    // register; held across all 8 o's so X is fetched from HBM exactly once.
    const f32x4 xf0 = *reinterpret_cast<const f32x4*>(X + nb * 64 + q * 8);
    const f32x4 xf1 = *reinterpret_cast<const f32x4*>(X + nb * 64 + q * 8 + 4);
    const f32x4 xf2 = *reinterpret_cast<const f32x4*>(X + nb * 64 + 32 + q * 8);
    const f32x4 xf3 = *reinterpret_cast<const f32x4*>(X + nb * 64 + 32 + q * 8 + 4);
    short8 xk0, xk1;
    #pragma unroll
    for (int j = 0; j < 4; ++j) {
        xk0[j]     = (short)f2bf(xf0[j]);
        xk0[4 + j] = (short)f2bf(xf1[j]);
        xk1[j]     = (short)f2bf(xf2[j]);
        xk1[4 + j] = (short)f2bf(xf3[j]);
    }

    #pragma unroll
    for (int o = 0; o < 8; ++o) {
        const unsigned short* wp = wmt + o * 4096;
        float* outp = out + o * O_STRIDE + nb * 64;
        #pragma unroll
        for (int ct = 0; ct < 4; ++ct) {
            const int c = ct * 16 + r;     // A-operand row (c index)
            // A frag straight from L2-resident WMt: 16B per lane, the wave
            // covers 16 full 64B lines (c-rows ct*16..ct*16+15, k-halves).
            short8 a0 = *reinterpret_cast<const short8*>(wp + c * 64 + q * 8);
            short8 a1 = *reinterpret_cast<const short8*>(wp + c * 64 + 32 + q * 8);
            f32x4 acc = {0.f, 0.f, 0.f, 0.f};
            acc = __builtin_amdgcn_mfma_f32_16x16x32_bf16(a0, xk0, acc, 0, 0, 0);
            acc = __builtin_amdgcn_mfma_f32_16x16x32_bf16(a1, xk1, acc, 0, 0, 0);
            // lane holds x1[nb][ct*16 + 4q + {0..3}] -> float4 store
            *reinterpret_cast<f32x4*>(outp + ct * 16 + q * 4) = acc;
        }
    }
}

extern "C" void kernel_launch(void* const* d_in, const int* in_sizes, int n_in,
                              void* d_out, int out_size, void* d_ws, size_t ws_size,
                              hipStream_t stream)
{
    const float* X    = (const float*)d_in[0];
    const float* dags = (const float*)d_in[1];
    const float* W    = (const float*)d_in[2];
    float* out = (float*)d_out;
    unsigned short* wmt = (unsigned short*)d_ws;   // 64 KB scratch

    prep_kernel<<<8, 256, 0, stream>>>(dags, W, wmt, out);
    gemm_kernel<<<NROWS / 64, 256, 0, stream>>>(X, wmt, out);
}

// Round 3
// 499.722 us; speedup vs baseline: 1.0150x; 1.0150x over previous
//
#include <hip/hip_runtime.h>

// Problem (all fp32 in/out): x1[o,n,c] = sum_p X[n,p] * (dags*W)[o,p,c]
//          plus dags passthrough and reg[o] = 0.001*sum(W^2).
// N=200000, D=64 (P=C=64), O=8.
// d_out (fp32): x1 (102,400,000) | dags (32,768) | reg (8).
//
// Session findings baked in:
//  - 1.639 GB workspace poison fill (~261 us @ 78% HBM peak) is UNCONDITIONAL
//    (R1: d_ws unused, fill unchanged). It is a fixed tax; use d_ws freely.
//  - NT loads/stores regressed (R1, +38 us): plain loads/stores only.
//  - L2-direct A-frags per MFMA regressed (R2, +43 us): per-MFMA memory
//    dependency at ~200cyc L2 latency. A-frags must be register-resident.
//  - R3 structure: one o per wave (8 waves/block), A-frags loaded ONCE per
//    block into 32 VGPRs, then pure streaming {X load -> cvt -> MFMA -> store}
//    with zero LDS and zero barriers. X reuse across the 8 waves via L1/L2.

typedef short short8 __attribute__((ext_vector_type(8)));   // 8 bf16 = 4 VGPRs (MFMA A/B frag)
typedef float f32x4 __attribute__((ext_vector_type(4)));    // MFMA C/D frag / float4

#define NROWS    200000
#define DAGS_OFF 102400000
#define REG_OFF  102432768
#define O_STRIDE 12800000    // 200000*64

#define ROWS_PER_BLOCK 160   // 5 tiles x 2 subtiles x 16 rows
#define GRID_GEMM      1250  // 1250 * 160 = 200000 exactly

__device__ __forceinline__ unsigned short f2bf(float f) {
    union { float f; unsigned int i; } v; v.f = f;
    unsigned int x = v.i;
    unsigned int r = (x + 0x7fffu + ((x >> 16) & 1u)) >> 16;   // RNE
    return (unsigned short)r;
}

// ---------------------------------------------------------------------------
// Prep: WMt[o][c][p] = bf16(dags[o][p][c] * W[o][p][c]) into ws (64 KB),
//       dags fp32 passthrough, reg[o] = 0.001 * sum(W[o]^2) fp32.
// One block per o, 256 threads.
// ---------------------------------------------------------------------------
__global__ __launch_bounds__(256) void prep_kernel(
    const float* __restrict__ dags,
    const float* __restrict__ W,
    unsigned short* __restrict__ wmt,
    float* __restrict__ out)
{
    const int o = blockIdx.x;
    const int t = threadIdx.x;
    const float* dg = dags + o * 4096;
    const float* w  = W    + o * 4096;
    unsigned short* wt = wmt + o * 4096;
    float* outd = out + DAGS_OFF + o * 4096;

    float s = 0.f;
    #pragma unroll
    for (int i = 0; i < 16; ++i) {
        int e = i * 256 + t;          // e = p*64 + c  (coalesced fp32 reads)
        int p = e >> 6, c = e & 63;
        float dv = dg[e];
        float wv = w[e];
        wt[c * 64 + p] = f2bf(dv * wv);   // transposed bf16 write (tiny, L2-resident)
        outd[e] = dv;                      // dags passthrough
        s += wv * wv;
    }
    // block reduction for reg
    #pragma unroll
    for (int off = 32; off > 0; off >>= 1) s += __shfl_down(s, off);
    __shared__ float red[4];
    if ((t & 63) == 0) red[t >> 6] = s;
    __syncthreads();
    if (t == 0) {
        out[REG_OFF + o] = 0.001f * (red[0] + red[1] + red[2] + red[3]);
    }
}

// ---------------------------------------------------------------------------
// Main: 512 threads = 8 waves; wave w owns o = w. A-fragments (the wave's
// entire WMt[o] slice, c-major) live in 32 VGPRs for the whole block.
// Block covers 160 contiguous rows = 5 tiles x 2 subtiles x 16 rows.
// Per 16-row subtile: 4 X loads -> 16 cvt -> 8 MFMA (reg-only) -> 4 stores.
// No LDS, no barriers, no per-MFMA memory dependency.
// Fragment math identical to the verified R0/R2 kernels:
//   lane: r=lane&15 (X row / D row), q=lane>>4 (k-chunk / D col quad)
//   A row c = ct*16 + r, halves at k=q*8 and 32+q*8
//   D: lane holds x1[nb][ct*16 + q*4 .. +3]
// ---------------------------------------------------------------------------
__global__ __launch_bounds__(512) void gemm_kernel(
    const float* __restrict__ X,
    const unsigned short* __restrict__ wmt,
    float* __restrict__ out)
{
    const int t    = threadIdx.x;
    const int o    = t >> 6;        // wave id == output head
    const int lane = t & 63;
    const int r    = lane & 15;
    const int q    = lane >> 4;

    // A-fragments: loaded once, register-resident (fully unrolled -> no scratch)
    const unsigned short* wp = wmt + o * 4096;
    short8 a[4][2];
    #pragma unroll
    for (int ct = 0; ct < 4; ++ct) {
        a[ct][0] = *reinterpret_cast<const short8*>(wp + (ct * 16 + r) * 64 + q * 8);
        a[ct][1] = *reinterpret_cast<const short8*>(wp + (ct * 16 + r) * 64 + 32 + q * 8);
    }

    const int rowbase = blockIdx.x * ROWS_PER_BLOCK;
    float* const outo = out + o * O_STRIDE;

    #pragma unroll
    for (int tile = 0; tile < 5; ++tile) {
        #pragma unroll
        for (int s = 0; s < 2; ++s) {
            const int nb = rowbase + tile * 32 + s * 16 + r;
            const float* xp = X + nb * 64;

            // X fragment (B operand): lane holds X[nb][q*8..q*8+7] and [+32]
            const f32x4 xf0 = *reinterpret_cast<const f32x4*>(xp + q * 8);
            const f32x4 xf1 = *reinterpret_cast<const f32x4*>(xp + q * 8 + 4);
            const f32x4 xf2 = *reinterpret_cast<const f32x4*>(xp + 32 + q * 8);
            const f32x4 xf3 = *reinterpret_cast<const f32x4*>(xp + 32 + q * 8 + 4);
            short8 xk0, xk1;
            #pragma unroll
            for (int j = 0; j < 4; ++j) {
                xk0[j]     = (short)f2bf(xf0[j]);
                xk0[4 + j] = (short)f2bf(xf1[j]);
                xk1[j]     = (short)f2bf(xf2[j]);
                xk1[4 + j] = (short)f2bf(xf3[j]);
            }

            float* outp = outo + nb * 64;
            #pragma unroll
            for (int ct = 0; ct < 4; ++ct) {
                f32x4 acc = {0.f, 0.f, 0.f, 0.f};
                acc = __builtin_amdgcn_mfma_f32_16x16x32_bf16(a[ct][0], xk0, acc, 0, 0, 0);
                acc = __builtin_amdgcn_mfma_f32_16x16x32_bf16(a[ct][1], xk1, acc, 0, 0, 0);
                *reinterpret_cast<f32x4*>(outp + ct * 16 + q * 4) = acc;
            }
        }
    }
}

extern "C" void kernel_launch(void* const* d_in, const int* in_sizes, int n_in,
                              void* d_out, int out_size, void* d_ws, size_t ws_size,
                              hipStream_t stream)
{
    const float* X    = (const float*)d_in[0];
    const float* dags = (const float*)d_in[1];
    const float* W    = (const float*)d_in[2];
    float* out = (float*)d_out;
    unsigned short* wmt = (unsigned short*)d_ws;   // 64 KB scratch

    prep_kernel<<<8, 256, 0, stream>>>(dags, W, wmt, out);
    gemm_kernel<<<GRID_GEMM, 512, 0, stream>>>(X, wmt, out);
}

// Round 4
// 456.916 us; speedup vs baseline: 1.1101x; 1.0937x over previous
//
#include <hip/hip_runtime.h>

// EXACT re-run of the round-0 best kernel (457.0 us on the previous session's
// container) as a cross-session A/B anchor. R1-R3 made large structural
// changes (NT, L2-direct, reg-resident/barrier-free) and all landed 495-507,
// i.e. within 2.4% of each other -- structure-insensitive. Hypothesis: the
// 457 -> ~500 gap is environment drift, not kernel regression. This run
// disambiguates before any further optimization.
//
// Problem (all fp32 in/out): x1[o,n,c] = sum_p X[n,p] * (dags*W)[o,p,c]
//          plus dags passthrough and reg[o] = 0.001*sum(W^2).
// N=200000, D=64 (P=C=64), O=8.
// d_out (fp32): x1 (102,400,000) | dags (32,768) | reg (8).

typedef short short8 __attribute__((ext_vector_type(8)));   // 8 bf16 = 4 VGPRs (MFMA A/B frag)
typedef float f32x4 __attribute__((ext_vector_type(4)));    // MFMA C/D frag / float4

#define NROWS    200000
#define DAGS_OFF 102400000
#define REG_OFF  102432768
#define O_STRIDE 12800000    // 200000*64

__device__ __forceinline__ unsigned short f2bf(float f) {
    union { float f; unsigned int i; } v; v.f = f;
    unsigned int x = v.i;
    unsigned int r = (x + 0x7fffu + ((x >> 16) & 1u)) >> 16;   // RNE
    return (unsigned short)r;
}

// ---------------------------------------------------------------------------
// Prep: WMt[o][c][p] = bf16(dags[o][p][c] * W[o][p][c]) into ws (64 KB),
//       dags fp32 passthrough, reg[o] = 0.001 * sum(W[o]^2) fp32.
// One block per o, 256 threads.
// ---------------------------------------------------------------------------
__global__ __launch_bounds__(256) void prep_kernel(
    const float* __restrict__ dags,
    const float* __restrict__ W,
    unsigned short* __restrict__ wmt,
    float* __restrict__ out)
{
    const int o = blockIdx.x;
    const int t = threadIdx.x;
    const float* dg = dags + o * 4096;
    const float* w  = W    + o * 4096;
    unsigned short* wt   = wmt + o * 4096;
    float* outd = out + DAGS_OFF + o * 4096;

    float s = 0.f;
    #pragma unroll
    for (int i = 0; i < 16; ++i) {
        int e = i * 256 + t;          // e = p*64 + c  (coalesced fp32 reads)
        int p = e >> 6, c = e & 63;
        float dv = dg[e];
        float wv = w[e];
        wt[c * 64 + p] = f2bf(dv * wv);   // transposed bf16 write (tiny, L2-absorbed)
        outd[e] = dv;                      // dags passthrough
        s += wv * wv;
    }
    // block reduction for reg
    #pragma unroll
    for (int off = 32; off > 0; off >>= 1) s += __shfl_down(s, off);
    __shared__ float red[4];
    if ((t & 63) == 0) red[t >> 6] = s;
    __syncthreads();
    if (t == 0) {
        out[REG_OFF + o] = 0.001f * (red[0] + red[1] + red[2] + red[3]);
    }
}

// ---------------------------------------------------------------------------
// Main: per block 64 rows of X, all 8 o's. MFMA 16x16x32 bf16, transposed
// trick: A = WMt tile (c-major), B = X rows. D lane holds fixed row n=lane&15,
// 4 consecutive c per reg-quad -> float4 stores.
// ---------------------------------------------------------------------------
__global__ __launch_bounds__(256) void gemm_kernel(
    const float* __restrict__ X,
    const unsigned short* __restrict__ wmt,
    float* __restrict__ out)
{
    // [oo][c][chunk] with chunk XOR-swizzle; 32 KB
    __shared__ short8 WMts[4][64][8];

    const int t    = threadIdx.x;
    const int w    = t >> 6;        // wave 0..3
    const int lane = t & 63;
    const int r    = lane & 15;     // B col (X row within tile) / A row (c)
    const int q    = lane >> 4;     // quad 0..3

    const int nb = blockIdx.x * 64 + w * 16 + r;   // this lane's X row

    // X fragment (MFMA B operand): lane holds X[nb][k], k = q*8..q*8+7 (+32).
    // fp32 loads (4x16B, coalesced within quad), convert to bf16 in-register;
    // held across all 8 o's so X is fetched from HBM exactly once.
    const f32x4 xf0 = *reinterpret_cast<const f32x4*>(X + nb * 64 + q * 8);
    const f32x4 xf1 = *reinterpret_cast<const f32x4*>(X + nb * 64 + q * 8 + 4);
    const f32x4 xf2 = *reinterpret_cast<const f32x4*>(X + nb * 64 + 32 + q * 8);
    const f32x4 xf3 = *reinterpret_cast<const f32x4*>(X + nb * 64 + 32 + q * 8 + 4);
    short8 xk0, xk1;
    #pragma unroll
    for (int j = 0; j < 4; ++j) {
        xk0[j]     = (short)f2bf(xf0[j]);
        xk0[4 + j] = (short)f2bf(xf1[j]);
        xk1[j]     = (short)f2bf(xf2[j]);
        xk1[4 + j] = (short)f2bf(xf3[j]);
    }

    #pragma unroll
    for (int phase = 0; phase < 2; ++phase) {
        // stage 4 o's of WMt (32 KB) into LDS, 16B chunks, XOR swizzle on chunk idx
        {
            const unsigned short* src = wmt + phase * 4 * 4096;
            #pragma unroll
            for (int i = 0; i < 8; ++i) {
                int g   = i * 256 + t;       // 2048 chunks total
                int oo  = g >> 9;            // 512 chunks per o
                int rem = g & 511;
                int c   = rem >> 3;
                int j   = rem & 7;
                short8 v = *reinterpret_cast<const short8*>(src + oo * 4096 + c * 64 + j * 8);
                WMts[oo][c][j ^ (c & 7)] = v;
            }
        }
        __syncthreads();

        #pragma unroll
        for (int oo = 0; oo < 4; ++oo) {
            const int o = phase * 4 + oo;
            float* outp = out + o * O_STRIDE + nb * 64;
            #pragma unroll
            for (int ct = 0; ct < 4; ++ct) {
                const int c = ct * 16 + r;     // A-operand row (c index); c&7 == r&7
                short8 a0 = WMts[oo][c][q       ^ (r & 7)];
                short8 a1 = WMts[oo][c][(4 + q) ^ (r & 7)];
                f32x4 acc = {0.f, 0.f, 0.f, 0.f};
                acc = __builtin_amdgcn_mfma_f32_16x16x32_bf16(a0, xk0, acc, 0, 0, 0);
                acc = __builtin_amdgcn_mfma_f32_16x16x32_bf16(a1, xk1, acc, 0, 0, 0);
                // lane holds x1[nb][ct*16 + 4q + {0..3}] -> float4 store
                *reinterpret_cast<f32x4*>(outp + ct * 16 + q * 4) = acc;
            }
        }
        __syncthreads();   // before restaging LDS in next phase
    }
}

extern "C" void kernel_launch(void* const* d_in, const int* in_sizes, int n_in,
                              void* d_out, int out_size, void* d_ws, size_t ws_size,
                              hipStream_t stream)
{
    const float* X    = (const float*)d_in[0];
    const float* dags = (const float*)d_in[1];
    const float* W    = (const float*)d_in[2];
    float* out = (float*)d_out;
    unsigned short* wmt = (unsigned short*)d_ws;   // 64 KB scratch

    prep_kernel<<<8, 256, 0, stream>>>(dags, W, wmt, out);
    gemm_kernel<<<NROWS / 64, 256, 0, stream>>>(X, wmt, out);
}

// Round 5
// 448.744 us; speedup vs baseline: 1.1303x; 1.0182x over previous
//
#include <hip/hip_runtime.h>

// Problem (all fp32 in/out): x1[o,n,c] = sum_p X[n,p] * (dags*W)[o,p,c]
//          plus dags passthrough and reg[o] = 0.001*sum(W^2).
// N=200000, D=64 (P=C=64), O=8.
// d_out (fp32): x1 (102,400,000) | dags (32,768) | reg (8).
//
// Session findings:
//  - 1.639 GB poison fill (~261 us) is unconditional and in the timed window.
//  - R4 anchor: environment stable to 0.01% (456.92 vs 456.97). R1(NT +38us),
//    R2(L2-direct +50us), R3(reg-resident/barrier-free +43us) were REAL
//    regressions; the R0 LDS-staged lockstep structure is the best base.
//  - R5 change: per-wave LDS-transpose store epilogue. MFMA-native stores are
//    16x64B chunks @256B stride per instruction (half-covered 128B lines ->
//    suspected fetch-on-write RFO: +410 MB hidden HBM reads). Transpose the
//    16x64 tile through wave-private LDS and store 4x 1KB fully-contiguous
//    instructions (every 128B line fully covered by one instruction).

typedef short short8 __attribute__((ext_vector_type(8)));   // 8 bf16 = 4 VGPRs (MFMA A/B frag)
typedef float f32x4 __attribute__((ext_vector_type(4)));    // MFMA C/D frag / float4

#define NROWS    200000
#define DAGS_OFF 102400000
#define REG_OFF  102432768
#define O_STRIDE 12800000    // 200000*64

__device__ __forceinline__ unsigned short f2bf(float f) {
    union { float f; unsigned int i; } v; v.f = f;
    unsigned int x = v.i;
    unsigned int r = (x + 0x7fffu + ((x >> 16) & 1u)) >> 16;   // RNE
    return (unsigned short)r;
}

// ---------------------------------------------------------------------------
// Prep: WMt[o][c][p] = bf16(dags[o][p][c] * W[o][p][c]) into ws (64 KB),
//       dags fp32 passthrough, reg[o] = 0.001 * sum(W[o]^2) fp32.
// One block per o, 256 threads.  (unchanged from R0)
// ---------------------------------------------------------------------------
__global__ __launch_bounds__(256) void prep_kernel(
    const float* __restrict__ dags,
    const float* __restrict__ W,
    unsigned short* __restrict__ wmt,
    float* __restrict__ out)
{
    const int o = blockIdx.x;
    const int t = threadIdx.x;
    const float* dg = dags + o * 4096;
    const float* w  = W    + o * 4096;
    unsigned short* wt   = wmt + o * 4096;
    float* outd = out + DAGS_OFF + o * 4096;

    float s = 0.f;
    #pragma unroll
    for (int i = 0; i < 16; ++i) {
        int e = i * 256 + t;          // e = p*64 + c  (coalesced fp32 reads)
        int p = e >> 6, c = e & 63;
        float dv = dg[e];
        float wv = w[e];
        wt[c * 64 + p] = f2bf(dv * wv);   // transposed bf16 write (tiny, L2-absorbed)
        outd[e] = dv;                      // dags passthrough
        s += wv * wv;
    }
    #pragma unroll
    for (int off = 32; off > 0; off >>= 1) s += __shfl_down(s, off);
    __shared__ float red[4];
    if ((t & 63) == 0) red[t >> 6] = s;
    __syncthreads();
    if (t == 0) {
        out[REG_OFF + o] = 0.001f * (red[0] + red[1] + red[2] + red[3]);
    }
}

// ---------------------------------------------------------------------------
// Main: per block 64 rows of X, all 8 o's. MFMA 16x16x32 bf16.
// NEW: accumulate the wave's full 16x64 tile (acc[4]), transpose it through a
// wave-private padded LDS buffer, then store 4x fully-contiguous 1KB wave
// instructions per (wave, o).
// ---------------------------------------------------------------------------
__global__ __launch_bounds__(256) void gemm_kernel(
    const float* __restrict__ X,
    const unsigned short* __restrict__ wmt,
    float* __restrict__ out)
{
    // [oo][c][chunk] with chunk XOR-swizzle; 32 KB
    __shared__ short8 WMts[4][64][8];
    // per-wave transpose buffer: 16 rows x (16+1 pad) chunks of 16B = 4352 B/wave
    __shared__ f32x4 TR[4][16 * 17];

    const int t    = threadIdx.x;
    const int w    = t >> 6;        // wave 0..3
    const int lane = t & 63;
    const int r    = lane & 15;     // B col (X row within tile) / A row (c)
    const int q    = lane >> 4;     // quad 0..3

    const int nb0 = blockIdx.x * 64 + w * 16;   // wave's 16-row tile base
    const int nb  = nb0 + r;                    // this lane's X row

    // X fragment (MFMA B operand): lane holds X[nb][k], k = q*8..q*8+7 (+32).
    const f32x4 xf0 = *reinterpret_cast<const f32x4*>(X + nb * 64 + q * 8);
    const f32x4 xf1 = *reinterpret_cast<const f32x4*>(X + nb * 64 + q * 8 + 4);
    const f32x4 xf2 = *reinterpret_cast<const f32x4*>(X + nb * 64 + 32 + q * 8);
    const f32x4 xf3 = *reinterpret_cast<const f32x4*>(X + nb * 64 + 32 + q * 8 + 4);
    short8 xk0, xk1;
    #pragma unroll
    for (int j = 0; j < 4; ++j) {
        xk0[j]     = (short)f2bf(xf0[j]);
        xk0[4 + j] = (short)f2bf(xf1[j]);
        xk1[j]     = (short)f2bf(xf2[j]);
        xk1[4 + j] = (short)f2bf(xf3[j]);
    }

    f32x4* const tb = TR[w];

    #pragma unroll
    for (int phase = 0; phase < 2; ++phase) {
        // stage 4 o's of WMt (32 KB) into LDS, 16B chunks, XOR swizzle on chunk idx
        {
            const unsigned short* src = wmt + phase * 4 * 4096;
            #pragma unroll
            for (int i = 0; i < 8; ++i) {
                int g   = i * 256 + t;       // 2048 chunks total
                int oo  = g >> 9;            // 512 chunks per o
                int rem = g & 511;
                int c   = rem >> 3;
                int j   = rem & 7;
                short8 v = *reinterpret_cast<const short8*>(src + oo * 4096 + c * 64 + j * 8);
                WMts[oo][c][j ^ (c & 7)] = v;
            }
        }
        __syncthreads();

        #pragma unroll
        for (int oo = 0; oo < 4; ++oo) {
            const int o = phase * 4 + oo;

            // compute the wave's full 16x64 tile: acc[ct] = rows nb0..nb0+15,
            // cols ct*16+q*4..+3 held per lane (r, q)
            f32x4 acc[4];
            #pragma unroll
            for (int ct = 0; ct < 4; ++ct) {
                const int c = ct * 16 + r;
                short8 a0 = WMts[oo][c][q       ^ (r & 7)];
                short8 a1 = WMts[oo][c][(4 + q) ^ (r & 7)];
                f32x4 z = {0.f, 0.f, 0.f, 0.f};
                z = __builtin_amdgcn_mfma_f32_16x16x32_bf16(a0, xk0, z, 0, 0, 0);
                acc[ct] = __builtin_amdgcn_mfma_f32_16x16x32_bf16(a1, xk1, z, 0, 0, 0);
            }

            // wave-local transpose: write (row=r, chunk=ct*4+q), padded row of 17
            #pragma unroll
            for (int ct = 0; ct < 4; ++ct)
                tb[r * 17 + ct * 4 + q] = acc[ct];

            // DS ops are in-order per wave; drain before cross-lane read-back
            asm volatile("s_waitcnt lgkmcnt(0)" ::: "memory");
            __builtin_amdgcn_sched_barrier(0);

            // read back lane-contiguous chunks and store 4x 1KB contiguous
            float* outp = out + o * O_STRIDE + nb0 * 64;
            #pragma unroll
            for (int j = 0; j < 4; ++j) {
                const int row = j * 4 + q;                 // (j*64+lane)>>4
                f32x4 v = tb[row * 17 + r];                // chunk (l&15) of row
                *reinterpret_cast<f32x4*>(outp + j * 256 + lane * 4) = v;
            }
            // no barrier needed: tb is wave-private, reused next oo after
            // the reads above complete (in-wave lgkmcnt ordering)
            asm volatile("s_waitcnt lgkmcnt(0)" ::: "memory");
        }
        __syncthreads();   // before restaging WMts in next phase
    }
}

extern "C" void kernel_launch(void* const* d_in, const int* in_sizes, int n_in,
                              void* d_out, int out_size, void* d_ws, size_t ws_size,
                              hipStream_t stream)
{
    const float* X    = (const float*)d_in[0];
    const float* dags = (const float*)d_in[1];
    const float* W    = (const float*)d_in[2];
    float* out = (float*)d_out;
    unsigned short* wmt = (unsigned short*)d_ws;   // 64 KB scratch

    prep_kernel<<<8, 256, 0, stream>>>(dags, W, wmt, out);
    gemm_kernel<<<NROWS / 64, 256, 0, stream>>>(X, wmt, out);
}